// Round 2
// baseline (95.461 us; speedup 1.0000x reference)
//
#include <hip/hip_runtime.h>
#include <hip/hip_bf16.h>

#define BROWS 131072
#define CCOLS 64

// 0.5 * weight for distance i (the 0.5 from relu(d) = 0.5*(d+|d|))
__host__ __device__ constexpr float WP(int i) {
    return 0.5f / ((float)BROWS * (float)(CCOLS - i));
}
// coefficient of prefix-sum p_m in the folded linear term
__host__ __device__ constexpr float CM(int m) {
    return WP(m) + WP(CCOLS - m);
}
// sum of WP(i) over the parity class this thread owns
__host__ __device__ constexpr float WSUM(int parity) {
    float s = 0.f;
    for (int i = 1; i < CCOLS; ++i)
        if ((i & 1) == parity) s += WP(i);
    return s;
}

// Per row: total += sum_i w_i * sum_j relu(y[j+i]-y[j]) with y[c]=x[c]+0.01c,
// split as 0.5*w_i*(linear telescoping term + sum |y[j+i]-y[j]|).
__global__ __launch_bounds__(256, 4) void mrl_kernel(
    const float* __restrict__ cand,   // [B, C] row-major
    const float* __restrict__ summ,   // [B]
    float* __restrict__ out)          // [1], pre-zeroed
{
    const int half = threadIdx.x >> 7;            // 0: even distances + summary, 1: odd distances
    const int row  = blockIdx.x * 128 + (threadIdx.x & 127);

    const float4* rp = reinterpret_cast<const float4*>(cand + (size_t)row * CCOLS);
    float x[CCOLS];
#pragma unroll
    for (int c4 = 0; c4 < CCOLS / 4; ++c4) {
        float4 v = rp[c4];
        x[4 * c4 + 0] = v.x;
        x[4 * c4 + 1] = v.y;
        x[4 * c4 + 2] = v.z;
        x[4 * c4 + 3] = v.w;
    }
    const float s = summ[row];

    // ---- summary |x - s| part (pre-transform), half 0 only ----
    float sa = 0.f;
    if (half == 0) {
        float sa0 = 0.f, sa1 = 0.f;
#pragma unroll
        for (int c = 0; c < CCOLS; c += 2) {
            sa0 += fabsf(x[c]     - s);
            sa1 += fabsf(x[c + 1] - s);
        }
        sa = sa0 + sa1;
    }

    // ---- transform: y[c] = x[c] + 0.01*c (margin folded into values) ----
#pragma unroll
    for (int c = 0; c < CCOLS; ++c)
        x[c] = fmaf(0.01f, (float)c, x[c]);

    // ---- T = sum of y (4-way tree) ----
    float t0 = 0.f, t1 = 0.f, t2 = 0.f, t3 = 0.f;
#pragma unroll
    for (int c = 0; c < CCOLS; c += 4) {
        t0 += x[c]; t1 += x[c + 1]; t2 += x[c + 2]; t3 += x[c + 3];
    }
    const float T = (t0 + t1) + (t2 + t3);

    float total = 0.f;

    // ---- streaming prefix sums fold the telescoping linear term ----
    // contribution = WSUM(half)*T - sum_{m in parity} CM(m)*p_m
    if (half == 0) {
        float p = 0.f;
#pragma unroll
        for (int m = 2; m <= 62; m += 2) {
            p += x[m - 2] + x[m - 1];
            total = fmaf(-CM(m), p, total);
        }
        total = fmaf(WSUM(0), T, total);
        // summary term: mean relu(x - s) = 0.5/(B*C) * (T0 - 64*s + sum|x-s|)
        const float T0 = T - 20.16f;  // sum of original x = T - 0.01*sum(c)
        total = fmaf(0.5f / ((float)BROWS * (float)CCOLS),
                     (T0 - 64.f * s) + sa, total);
    } else {
        float p = x[0];
        total = fmaf(-CM(1), p, total);
#pragma unroll
        for (int m = 3; m <= 63; m += 2) {
            p += x[m - 2] + x[m - 1];
            total = fmaf(-CM(m), p, total);
        }
        total = fmaf(WSUM(1), T, total);
    }

    // ---- |difference| pair sums, 2 ops/pair (sub + add-with-abs-modifier) ----
    if (half == 0) {
#pragma unroll
        for (int i = 2; i < CCOLS; i += 2) {
            float a0 = 0.f, a1 = 0.f;
#pragma unroll
            for (int j = 0; j + i < CCOLS; j += 2) {
                a0 += fabsf(x[j + i] - x[j]);
                if (j + i + 1 < CCOLS) a1 += fabsf(x[j + i + 1] - x[j + 1]);
            }
            total = fmaf(WP(i), a0 + a1, total);
        }
    } else {
#pragma unroll
        for (int i = 1; i < CCOLS; i += 2) {
            float a0 = 0.f, a1 = 0.f;
#pragma unroll
            for (int j = 0; j + i < CCOLS; j += 2) {
                a0 += fabsf(x[j + i] - x[j]);
                if (j + i + 1 < CCOLS) a1 += fabsf(x[j + i + 1] - x[j + 1]);
            }
            total = fmaf(WP(i), a0 + a1, total);
        }
    }

    // ---- wave64 + block reduction, one atomic per block ----
#pragma unroll
    for (int off = 32; off > 0; off >>= 1)
        total += __shfl_down(total, off, 64);

    __shared__ float ws[4];
    const int lane = threadIdx.x & 63;
    const int w = threadIdx.x >> 6;
    if (lane == 0) ws[w] = total;
    __syncthreads();
    if (threadIdx.x == 0) {
        float t = ws[0] + ws[1] + ws[2] + ws[3];
        atomicAdd(out, t);
    }
}

extern "C" void kernel_launch(void* const* d_in, const int* in_sizes, int n_in,
                              void* d_out, int out_size, void* d_ws, size_t ws_size,
                              hipStream_t stream) {
    const float* cand = (const float*)d_in[0];
    const float* summ = (const float*)d_in[1];
    float* out = (float*)d_out;

    // d_out is re-poisoned to 0xAA before every timed replay — zero it here.
    hipMemsetAsync(out, 0, sizeof(float), stream);

    const int threads = 256;
    const int blocks = BROWS / 128;  // 1024 blocks: 2 threads per row (parity split)
    mrl_kernel<<<blocks, threads, 0, stream>>>(cand, summ, out);
}